// Round 7
// baseline (161.012 us; speedup 1.0000x reference)
//
#include <hip/hip_runtime.h>

// FNO spectral convolution, truncated separable DFT formulation.
// B=8, H=W=256, C_IN=C_OUT=64, modes 32 x 17 (rows fftshift-centered: k_m = m-16).
//
// ws layout (floats):
//   twA [256 w][17 n][2]  : 8704          cos/sin of 2*pi*n*w/256
//   twB [256 h][32 m][2]  : 16384         cos/sin of 2*pi*(m-16)*h/256
//   G   [B][H][17][64][2] : 4456448       W-direction DFT of x       (aliased by Z after k2a)
//   T   [B][H][17][64][2] : 4456448       mode-mixed, inverse-H DFT  (aliased by P before k2c)
//
//   P (partial xs) [4 hq][136 bn][32 m][64 i][2] = 2228224 floats -> lives in T's slot
//   Z [8 b][17 n][32 m][64 o][2] = 557056 floats                  -> lives in G's slot
// Liveness: k1 writes G; k2a reads G, writes P(T); k2b reads P, writes Z(G);
//           k2c reads Z, writes T (P dead); k3 reads T. No aliasing within a kernel.
//
// k1/k3 process TWO (b,h) rows per block: one 34-float wave-uniform twiddle
// s_load batch feeds 136 FLOPs (2 rows x 17 modes x cmul) -> SMEM latency
// amortized 2x vs one-row version (round-5 lesson: low FMA density per
// scalar-load batch -> 10% VALUBusy stall-bound).

#define NB 8
#define NH 256
#define NW 256
#define NC 64
#define NM1 32
#define NM2 17
#define HQ 4

__global__ void k0_tw(float* __restrict__ twA, float* __restrict__ twB) {
    const float STEP = 0.02454369260617026f; // 2*pi/256
    int t = blockIdx.x * 256 + threadIdx.x;
    if (t < 256 * 17) {
        int w = t / 17, n = t % 17;
        int ph = (n * w) & 255;
        float ang = (float)ph * STEP;
        twA[t * 2 + 0] = cosf(ang);
        twA[t * 2 + 1] = sinf(ang);
    }
    if (t < 256 * 32) {
        int h = t >> 5, m = t & 31;
        int ph = ((m - 16) * h) & 255; // two's complement & 255 == mod 256
        float ang = (float)ph * STEP;
        twB[t * 2 + 0] = cosf(ang);
        twB[t * 2 + 1] = sinf(ang);
    }
}

// K1: per block: TWO rows (bh0, bh0+1). G[n][i] = sum_w x[bh,w,i] * e^{-2pi i n w/256}
// 256 threads = lane i (64) x wave wq (4 w-quarters). x loaded directly from
// global (no intra-block reuse -> staging is pure overhead). Cross-wave reduce
// via 34.8 KB LDS in two passes (row0 then row1) -> 4 blocks/CU.
__global__ __launch_bounds__(256) void k1_fwdW(const float* __restrict__ x,
                                               const float* __restrict__ twA,
                                               float* __restrict__ G) {
    __shared__ float lre[4][17][64];
    __shared__ float lim[4][17][64];
    const int tid = threadIdx.x;
    const int i = tid & 63;
    const int wq_u = __builtin_amdgcn_readfirstlane(tid >> 6);
    const int bh0 = blockIdx.x * 2;

    float ar0[17], ai0[17], ar1[17], ai1[17];
    #pragma unroll
    for (int n = 0; n < 17; ++n) { ar0[n] = 0.f; ai0[n] = 0.f; ar1[n] = 0.f; ai1[n] = 0.f; }

    const float* xb0 = x + (size_t)bh0 * (NW * NC) + (size_t)wq_u * 64 * 64 + i;
    const float* xb1 = xb0 + NW * NC;
    #pragma unroll 2
    for (int ww = 0; ww < 64; ++ww) {
        float xv0 = xb0[(size_t)ww * 64];              // coalesced 256B/wave
        float xv1 = xb1[(size_t)ww * 64];
        const float* tw = twA + (wq_u * 64 + ww) * 34; // wave-uniform -> s_load
        #pragma unroll
        for (int n = 0; n < 17; ++n) {
            float c = tw[2 * n], s = tw[2 * n + 1];
            ar0[n] = fmaf(xv0, c, ar0[n]);
            ai0[n] = fmaf(-xv0, s, ai0[n]);            // e^{-i..}
            ar1[n] = fmaf(xv1, c, ar1[n]);
            ai1[n] = fmaf(-xv1, s, ai1[n]);
        }
    }

    // ---- reduce + store row 0 ----
    #pragma unroll
    for (int n = 0; n < 17; ++n) { lre[wq_u][n][i] = ar0[n]; lim[wq_u][n][i] = ai0[n]; }
    __syncthreads();
    float2* G0 = (float2*)G + (size_t)bh0 * 17 * 64;
    for (int n = wq_u; n < 17; n += 4) {
        float re = (lre[0][n][i] + lre[1][n][i]) + (lre[2][n][i] + lre[3][n][i]);
        float im = (lim[0][n][i] + lim[1][n][i]) + (lim[2][n][i] + lim[3][n][i]);
        G0[n * 64 + i] = make_float2(re, im);
    }
    __syncthreads();
    // ---- reduce + store row 1 ----
    #pragma unroll
    for (int n = 0; n < 17; ++n) { lre[wq_u][n][i] = ar1[n]; lim[wq_u][n][i] = ai1[n]; }
    __syncthreads();
    float2* G1 = G0 + 17 * 64;
    for (int n = wq_u; n < 17; n += 4) {
        float re = (lre[0][n][i] + lre[1][n][i]) + (lre[2][n][i] + lre[3][n][i]);
        float im = (lim[0][n][i] + lim[1][n][i]) + (lim[2][n][i] + lim[3][n][i]);
        G1[n * 64 + i] = make_float2(re, im);
    }
}

// K2a: partial H-DFT. grid (136 bn, 4 hq), 256 threads = lane i x wave q (8 m's each).
// P[hq][bn][m][i] = sum_{h in 64-chunk} G[b,h,n,i] * e^{-2pi i (m-16) h/256}
__global__ __launch_bounds__(256) void k2a_hdft(const float* __restrict__ G,
                                                const float* __restrict__ twB,
                                                float* __restrict__ P) {
    const int bn = blockIdx.x;   // b*17+n
    const int b = bn / 17, n = bn % 17;
    const int hq = blockIdx.y;   // 0..3
    const int t = threadIdx.x;
    const int lane = t & 63;     // i
    const int q_u = __builtin_amdgcn_readfirstlane(t >> 6);

    float ar[8], ai[8];
    #pragma unroll
    for (int j = 0; j < 8; ++j) { ar[j] = 0.f; ai[j] = 0.f; }

    const float2* Gb = (const float2*)G + ((size_t)b * 256 * 17 + n) * 64 + lane;
    #pragma unroll 2
    for (int hh = 0; hh < 64; ++hh) {
        int h = hq * 64 + hh;
        float2 g = Gb[(size_t)h * (17 * 64)];
        const float* tw = twB + (h * 32 + q_u * 8) * 2; // wave-uniform -> s_load
        #pragma unroll
        for (int j = 0; j < 8; ++j) {
            float c = tw[2 * j], s = tw[2 * j + 1];
            ar[j] = fmaf(g.x, c, fmaf(g.y, s, ar[j]));   // conj twiddle
            ai[j] = fmaf(g.y, c, fmaf(-g.x, s, ai[j]));
        }
    }
    float2* Pp = (float2*)P + (((size_t)hq * 136 + bn) * 32 + q_u * 8) * 64 + lane;
    #pragma unroll
    for (int j = 0; j < 8; ++j) Pp[j * 64] = make_float2(ar[j], ai[j]);
}

// K2b: reduce 4 hq-partials + mode mix. grid 544 = n*32+m, 256 threads = lane o x wave q (2 b's).
// Z[b][n][m][o] = scale * sum_i xs[b,n,m,i] * (Wr + i Wi)[m,n,i,o]
__global__ __launch_bounds__(256) void k2b_mix(const float* __restrict__ P,
                                               const float* __restrict__ Wr,
                                               const float* __restrict__ Wi,
                                               float* __restrict__ Z) {
    __shared__ float2 xs[8 * 64]; // [b][i]
    const int mn = blockIdx.x;
    const int m = mn & 31, n = mn >> 5;
    const int t = threadIdx.x;
    const int lane = t & 63;
    const int q = t >> 6;

    #pragma unroll
    for (int r = 0; r < 2; ++r) {
        int v = t + r * 256;               // v = b*64 + i
        int b = v >> 6, i = v & 63;
        const float2* Pp = (const float2*)P + (((size_t)(b * 17 + n)) * 32 + m) * 64 + i;
        float re = 0.f, im = 0.f;
        #pragma unroll
        for (int hq = 0; hq < HQ; ++hq) {
            float2 pv = Pp[(size_t)hq * (136 * 32 * 64)];
            re += pv.x; im += pv.y;
        }
        xs[v] = make_float2(re, im);
    }
    __syncthreads();

    const float scale = (n == 0 ? 1.0f : 2.0f) * (1.0f / 65536.0f);
    const int b0 = q * 2, b1 = b0 + 1;
    float z0r = 0, z0i = 0, z1r = 0, z1i = 0;
    const float* Wrp = Wr + (((size_t)m * 17 + n) * 64) * 64 + lane;
    const float* Wip = Wi + (((size_t)m * 17 + n) * 64) * 64 + lane;
    for (int i = 0; i < 64; ++i) {
        float wr = Wrp[(size_t)i * 64], wi = Wip[(size_t)i * 64];
        float2 x0 = xs[b0 * 64 + i], x1 = xs[b1 * 64 + i]; // LDS broadcast
        z0r = fmaf(x0.x, wr, fmaf(-x0.y, wi, z0r));
        z0i = fmaf(x0.x, wi, fmaf(x0.y, wr, z0i));
        z1r = fmaf(x1.x, wr, fmaf(-x1.y, wi, z1r));
        z1i = fmaf(x1.x, wi, fmaf(x1.y, wr, z1i));
    }
    float2* Zp = (float2*)Z;
    Zp[(((size_t)b0 * 17 + n) * 32 + m) * 64 + lane] = make_float2(z0r * scale, z0i * scale);
    Zp[(((size_t)b1 * 17 + n) * 32 + m) * 64 + lane] = make_float2(z1r * scale, z1i * scale);
}

// K2c: inverse H-DFT. grid (136 bn, 8 hq), 256 threads = lane o x wave q (8 h's each).
// T[b,h,n,o] = sum_m Z[b,n,m,o] * e^{+2pi i (m-16) h/256}
__global__ __launch_bounds__(256) void k2c_ihdft(const float* __restrict__ Z,
                                                 const float* __restrict__ twB,
                                                 float* __restrict__ T) {
    __shared__ float2 zs[32 * 64]; // [m][o], 16 KB
    const int bn = blockIdx.x;
    const int b = bn / 17, n = bn % 17;
    const int hq = blockIdx.y;
    const int t = threadIdx.x;
    const int lane = t & 63;
    const int q_u = __builtin_amdgcn_readfirstlane(t >> 6);

    const float2* Zp = (const float2*)Z + (((size_t)b * 17 + n) * 32) * 64;
    #pragma unroll
    for (int r = 0; r < 8; ++r) zs[r * 256 + t] = Zp[r * 256 + t];
    __syncthreads();

    float2* Tb = (float2*)T + ((size_t)b * 256 * 17 + n) * 64 + lane;
    #pragma unroll 2
    for (int jj = 0; jj < 8; ++jj) {
        int h = hq * 32 + q_u * 8 + jj;
        const float* tw = twB + h * 64;        // wave-uniform -> s_load
        float re0 = 0, im0 = 0, re1 = 0, im1 = 0;
        #pragma unroll
        for (int m = 0; m < 32; m += 2) {
            float2 z0 = zs[m * 64 + lane];
            float c0 = tw[2 * m + 0], s0 = tw[2 * m + 1];
            re0 = fmaf(z0.x, c0, fmaf(-z0.y, s0, re0));  // e^{+i..}
            im0 = fmaf(z0.x, s0, fmaf(z0.y, c0, im0));
            float2 z1 = zs[(m + 1) * 64 + lane];
            float c1 = tw[2 * m + 2], s1 = tw[2 * m + 3];
            re1 = fmaf(z1.x, c1, fmaf(-z1.y, s1, re1));
            im1 = fmaf(z1.x, s1, fmaf(z1.y, c1, im1));
        }
        Tb[(size_t)h * (17 * 64)] = make_float2(re0 + re1, im0 + im1);
    }
}

// K3: per block: TWO rows (bh0, bh0+1). y[bh,w,o] = sum_n Re(T[bh,n,o] e^{+2pi i n w/256});
// c_n folded into Z. One 34-float twiddle s_load batch feeds 136 FLOPs.
__global__ __launch_bounds__(256) void k3_invW(const float* __restrict__ T,
                                               const float* __restrict__ twA,
                                               float* __restrict__ y) {
    const int tid = threadIdx.x;
    const int o = tid & 63;
    const int wq_u = __builtin_amdgcn_readfirstlane(tid >> 6);
    const int bh0 = blockIdx.x * 2;

    const float2* T0 = (const float2*)T + (size_t)bh0 * 17 * 64;
    const float2* T1 = T0 + 17 * 64;
    float tr0[17], ti0[17], tr1[17], ti1[17];
    #pragma unroll
    for (int n = 0; n < 17; ++n) {
        float2 v0 = T0[n * 64 + o];
        tr0[n] = v0.x; ti0[n] = v0.y;
        float2 v1 = T1[n * 64 + o];
        tr1[n] = v1.x; ti1[n] = v1.y;
    }

    float* yb0 = y + (size_t)bh0 * (NW * NC);
    float* yb1 = yb0 + NW * NC;
    #pragma unroll 2
    for (int ww = 0; ww < 64; ++ww) {
        int w = wq_u * 64 + ww;
        const float* tw = twA + (size_t)w * 34;  // wave-uniform -> s_load
        float a0 = 0.f, a1 = 0.f, b0 = 0.f, b1 = 0.f;
        #pragma unroll
        for (int n = 0; n < 16; n += 2) {
            float c0 = tw[2 * n + 0], s0 = tw[2 * n + 1];
            float c1 = tw[2 * n + 2], s1 = tw[2 * n + 3];
            a0 = fmaf(tr0[n + 0], c0, fmaf(-ti0[n + 0], s0, a0));
            b0 = fmaf(tr1[n + 0], c0, fmaf(-ti1[n + 0], s0, b0));
            a1 = fmaf(tr0[n + 1], c1, fmaf(-ti0[n + 1], s1, a1));
            b1 = fmaf(tr1[n + 1], c1, fmaf(-ti1[n + 1], s1, b1));
        }
        float c16 = tw[32], s16 = tw[33];
        a0 = fmaf(tr0[16], c16, fmaf(-ti0[16], s16, a0));
        b0 = fmaf(tr1[16], c16, fmaf(-ti1[16], s16, b0));
        yb0[(size_t)w * 64 + o] = a0 + a1;
        yb1[(size_t)w * 64 + o] = b0 + b1;
    }
}

extern "C" void kernel_launch(void* const* d_in, const int* in_sizes, int n_in,
                              void* d_out, int out_size, void* d_ws, size_t ws_size,
                              hipStream_t stream) {
    (void)in_sizes; (void)n_in; (void)out_size; (void)ws_size;
    const float* x  = (const float*)d_in[0];
    const float* Wr = (const float*)d_in[1];
    const float* Wi = (const float*)d_in[2];
    float* out = (float*)d_out;
    float* ws  = (float*)d_ws;

    float* twA = ws;                 // 8704 floats
    float* twB = ws + 8704;          // 16384 floats
    float* G   = ws + 25088;         // 4456448 floats
    float* T   = G + 4456448;        // 4456448 floats
    float* P   = T;                  // alias: partials (2228224 floats) live in T's slot
    float* Z   = G;                  // alias: Z (2.2 MB) lives in dead G's slot

    k0_tw<<<32, 256, 0, stream>>>(twA, twB);
    k1_fwdW<<<NB * NH / 2, 256, 0, stream>>>(x, twA, G);
    k2a_hdft<<<dim3(NB * NM2, HQ), 256, 0, stream>>>(G, twB, P);
    k2b_mix<<<NM1 * NM2, 256, 0, stream>>>(P, Wr, Wi, Z);
    k2c_ihdft<<<dim3(NB * NM2, 8), 256, 0, stream>>>(Z, twB, T);
    k3_invW<<<NB * NH / 2, 256, 0, stream>>>(T, twA, out);
}